// Round 4
// baseline (103.128 us; speedup 1.0000x reference)
//
#include <hip/hip_runtime.h>
#include <math.h>

// DynamicSparseAttention via MFMA flash (f16 operands, fp32 accum):
// out = (O5 + Z^4 O1) / (S5 + Z^4 S1), e = 2^(s*log2e - m'), Z = S1.
// Swapped QK^T (mfma(K,Q)) so each lane owns one query's score row.
// R4: 4 blocks/CU (QB=64), conflict-free b128 V staging, pk-cvt, setprio.

typedef _Float16 h8 __attribute__((ext_vector_type(8)));
typedef _Float16 h4 __attribute__((ext_vector_type(4)));
typedef _Float16 h2 __attribute__((ext_vector_type(2)));
typedef float f4 __attribute__((ext_vector_type(4)));

constexpr int Lc = 2048, Sc = 2048, Hc = 16;
constexpr int KB = 64, NT = Sc / KB;
constexpr float LOG2E = 1.4426950408889634f;

__device__ __forceinline__ f4 mm(h8 a, h8 b, f4 c) {
  return __builtin_amdgcn_mfma_f32_16x16x32_f16(a, b, c, 0, 0, 0);
}
__device__ __forceinline__ h2 pk(float a, float b) {
  return __builtin_bit_cast(h2, __builtin_amdgcn_cvt_pkrtz(a, b));
}

__global__ __launch_bounds__(256, 4) void dsa_mfma(
    const float* __restrict__ Q, const float* __restrict__ K,
    const float* __restrict__ V, float* __restrict__ O) {
  __shared__ __align__(16) _Float16 Ks[64 * 64];        // K tile [k][e], pos = e ^ 8*(k&7)
  __shared__ __align__(16) _Float16 Vts[64 * 64];       // V^T tile [d][k], pos = k ^ 8*(d&7)
  __shared__ __align__(16) _Float16 Ps[4][2][16 * 64];  // per-wave P (e, e5) [q][k]

  const int tid = threadIdx.x;
  const int w = tid >> 6, lane = tid & 63, lq = lane & 15, lg = lane >> 4;
  const int kxor = (lq & 7) << 3;

  // XCD-bijective swizzle: 1024 blocks = 8 XCD x 128; each XCD owns 4 heads.
  const int blk = blockIdx.x;
  const int ww = (blk & 7) * 128 + (blk >> 3);
  const int qtb = ww & 31, bh = ww >> 5;
  const int b = bh >> 4, h = bh & 15;

  const size_t base = ((size_t)b * Sc * Hc + h) * 64;  // row stride = Hc*64 = 1024 floats
  const float* Qb = Q + base;
  const float* Kb = K + base;
  const float* Vb = V + base;
  const int q0 = qtb * 64 + w * 16;

  // ---- Q fragments to registers, scaled by log2e ----
  h8 qf[2];
#pragma unroll
  for (int kk = 0; kk < 2; ++kk) {
    const float* p = Qb + (size_t)(q0 + lq) * 1024 + kk * 32 + lg * 8;
    f4 a = *(const f4*)p, c = *(const f4*)(p + 4);
#pragma unroll
    for (int i = 0; i < 4; ++i) {
      qf[kk][i] = (_Float16)(a[i] * LOG2E);
      qf[kk][4 + i] = (_Float16)(c[i] * LOG2E);
    }
  }

  f4 O1[4] = {}, O5[4] = {};
  float mr = -INFINITY, S1 = 0.f, S5 = 0.f;

  // staging registers
  f4 kf[4];
  float vreg[2][8];
  const int krow_ = tid >> 4, kc4 = tid & 15;     // K: rows krow_+16i, 16B col kc4
  const int vd = tid & 63, vo0 = (tid >> 6) * 2;  // V: d-column vd, k-octets vo0,vo0+1

  auto LOADK = [&](int k0) {
#pragma unroll
    for (int i = 0; i < 4; ++i)
      kf[i] = *(const f4*)(Kb + (size_t)(k0 + i * 16 + krow_) * 1024 + kc4 * 4);
  };
  auto LOADV = [&](int k0) {  // gather 8 k-values per d-column: coalesced 256B/instr
#pragma unroll
    for (int i = 0; i < 2; ++i) {
      const float* p = Vb + (size_t)(k0 + (vo0 + i) * 8) * 1024 + vd;
#pragma unroll
      for (int j = 0; j < 8; ++j) vreg[i][j] = p[(size_t)j * 1024];
    }
  };
  auto STORE = [&]() {
#pragma unroll
    for (int i = 0; i < 4; ++i) {
      int krow = i * 16 + krow_;
      h2 a = pk(kf[i][0], kf[i][1]);
      h2 bb = pk(kf[i][2], kf[i][3]);
      h4 hh = {a[0], a[1], bb[0], bb[1]};
      *(h4*)&Ks[krow * 64 + ((kc4 * 4) ^ ((krow & 7) << 3))] = hh;
    }
#pragma unroll
    for (int i = 0; i < 2; ++i) {
      h8 hh;
#pragma unroll
      for (int u = 0; u < 4; ++u) {
        h2 t = pk(vreg[i][2 * u], vreg[i][2 * u + 1]);
        hh[2 * u] = t[0];
        hh[2 * u + 1] = t[1];
      }
      *(h8*)&Vts[vd * 64 + (((vo0 + i) * 8) ^ ((vd & 7) << 3))] = hh;
    }
  };

  LOADK(0);
  LOADV(0);

#pragma unroll 1
  for (int ks = 0; ks < NT; ++ks) {
    __syncthreads();  // prior tile's consumers done with Ks/Vts
    STORE();
    if (ks + 1 < NT) {  // prefetch next tile; latency hides under compute
      LOADK((ks + 1) * KB);
      LOADV((ks + 1) * KB);
    }
    __syncthreads();  // staged tile visible

    // ---- QK^T (swapped): sc[mt] = D[k][q], q = lq ----
    f4 sc[4] = {};
    __builtin_amdgcn_s_setprio(1);
#pragma unroll
    for (int kk = 0; kk < 2; ++kk)
#pragma unroll
      for (int mt = 0; mt < 4; ++mt) {
        h8 kf8 = *(const h8*)&Ks[(mt * 16 + lq) * 64 + ((kk * 32 + lg * 8) ^ kxor)];
        sc[mt] = mm(kf8, qf[kk], sc[mt]);
      }
    __builtin_amdgcn_s_setprio(0);

    // ---- online softmax (log2 domain), write P tiles ----
    float tm = -INFINITY;
#pragma unroll
    for (int mt = 0; mt < 4; ++mt)
#pragma unroll
      for (int r = 0; r < 4; ++r) tm = fmaxf(tm, sc[mt][r]);
    tm = fmaxf(tm, __shfl_xor(tm, 16));
    tm = fmaxf(tm, __shfl_xor(tm, 32));
    if (__any(tm > mr)) {  // rescale only on a new running max
      float nm = fmaxf(mr, tm);
      float f = __builtin_amdgcn_exp2f(mr - nm);
      float f2 = f * f, f5 = f2 * f2 * f;
      mr = nm;
      S1 *= f;
      S5 *= f5;
#pragma unroll
      for (int dt = 0; dt < 4; ++dt) {
        O1[dt] *= f;
        O5[dt] *= f5;
      }
    }
    float t1 = 0.f, t5 = 0.f;
#pragma unroll
    for (int mt = 0; mt < 4; ++mt) {
      float e[4], e5[4];
#pragma unroll
      for (int r = 0; r < 4; ++r) {
        e[r] = __builtin_amdgcn_exp2f(sc[mt][r] - mr);
        float e2 = e[r] * e[r];
        e5[r] = e2 * e2 * e[r];
        t1 += e[r];
        t5 += e5[r];
      }
      h2 a = pk(e[0], e[1]);
      h2 bb = pk(e[2], e[3]);
      h4 pe = {a[0], a[1], bb[0], bb[1]};
      h2 c = pk(e5[0], e5[1]);
      h2 d = pk(e5[2], e5[3]);
      h4 p5 = {c[0], c[1], d[0], d[1]};
      int pcol = (mt * 16 + lg * 4) ^ kxor;
      *(h4*)&Ps[w][0][lq * 64 + pcol] = pe;
      *(h4*)&Ps[w][1][lq * 64 + pcol] = p5;
    }
    t1 += __shfl_xor(t1, 16);
    t1 += __shfl_xor(t1, 32);
    t5 += __shfl_xor(t5, 16);
    t5 += __shfl_xor(t5, 32);
    S1 += t1;
    S5 += t5;

    // ---- PV (dual): O^T[d][q] += V^T P ----
#pragma unroll
    for (int k2 = 0; k2 < 2; ++k2) {
      const int rc = (k2 * 32 + lg * 8) ^ kxor;
      h8 be = *(const h8*)&Ps[w][0][lq * 64 + rc];
      h8 b5 = *(const h8*)&Ps[w][1][lq * 64 + rc];
      h8 vf[4];
#pragma unroll
      for (int dt = 0; dt < 4; ++dt)
        vf[dt] = *(const h8*)&Vts[(dt * 16 + lq) * 64 + rc];
      __builtin_amdgcn_s_setprio(1);
#pragma unroll
      for (int dt = 0; dt < 4; ++dt) {
        O1[dt] = mm(vf[dt], be, O1[dt]);
        O5[dt] = mm(vf[dt], b5, O5[dt]);
      }
      __builtin_amdgcn_s_setprio(0);
    }
  }

  // ---- epilogue: combine and normalize ----
  const float z = S1, z2 = z * z, z4 = z2 * z2;
  const float inv = 1.0f / (S5 + z4 * S1);
#pragma unroll
  for (int dt = 0; dt < 4; ++dt) {
    f4 o = (O5[dt] + z4 * O1[dt]) * inv;
    *(f4*)(O + base + (size_t)(q0 + lq) * 1024 + dt * 16 + lg * 4) = o;
  }
}

extern "C" void kernel_launch(void* const* d_in, const int* in_sizes, int n_in,
                              void* d_out, int out_size, void* d_ws, size_t ws_size,
                              hipStream_t stream) {
  const float* q = (const float*)d_in[0];
  const float* k = (const float*)d_in[1];
  const float* v = (const float*)d_in[2];
  float* o = (float*)d_out;
  dsa_mfma<<<dim3(1024), dim3(256), 0, stream>>>(q, k, v, o);
}

// Round 5
// 93.147 us; speedup vs baseline: 1.1072x; 1.1072x over previous
//
#include <hip/hip_runtime.h>
#include <math.h>

// DynamicSparseAttention via MFMA flash (f16 operands, fp32 accum):
// out = (O5 + Z^4 O1) / (S5 + Z^4 S1), e = 2^(s*log2e - m'), Z = S1.
// R5: 32x32x16 MFMA, in-register P (cvt_pk + permlane32_swap),
//     double-buffered K/V LDS with ONE barrier per tile.

typedef _Float16 h8 __attribute__((ext_vector_type(8)));
typedef float f4 __attribute__((ext_vector_type(4)));
typedef float f16v __attribute__((ext_vector_type(16)));
typedef unsigned int u4v __attribute__((ext_vector_type(4)));

constexpr int Sc = 2048, Hc = 16;
constexpr int KB = 64, NT = Sc / KB;
constexpr float LOG2E = 1.4426950408889634f;

__device__ __forceinline__ f16v mm32(h8 a, h8 b, f16v c) {
  return __builtin_amdgcn_mfma_f32_32x32x16_f16(a, b, c, 0, 0, 0);
}
__device__ __forceinline__ unsigned pku(float a, float b) {
  return __builtin_bit_cast(unsigned, __builtin_amdgcn_cvt_pkrtz(a, b));
}

__global__ __launch_bounds__(256, 2) void dsa_mfma(
    const float* __restrict__ Q, const float* __restrict__ K,
    const float* __restrict__ V, float* __restrict__ O) {
  __shared__ __align__(16) _Float16 Ks[2][64 * 64];   // [k][e], elem col ^= 8*(k&7)
  __shared__ __align__(16) _Float16 Vts[2][64 * 64];  // [d][k], elem col ^= 8*(d&7)

  const int tid = threadIdx.x;
  const int w = tid >> 6, lane = tid & 63, lm = lane & 31, hi = lane >> 5;
  const int swz = (lm & 7) << 3;

  // XCD-bijective swizzle: 512 blocks = 8 XCD x 64; each XCD owns 4 heads.
  const int blk = blockIdx.x;
  const int ww = (blk & 7) * 64 + (blk >> 3);
  const int qtb = ww & 15, bh = ww >> 4;
  const int b = bh >> 4, h = bh & 15;

  const size_t base = ((size_t)b * Sc * Hc + h) * 64;  // row stride = 1024 floats
  const float* Qb = Q + base;
  const float* Kb = K + base;
  const float* Vb = V + base;
  const int q0 = qtb * 128 + w * 32;

  // ---- Q fragments (B-operand): lane holds Q[q0+lm][s*16 + hi*8 + j]*log2e ----
  h8 qf[4];
#pragma unroll
  for (int s = 0; s < 4; ++s) {
    const float* p = Qb + (size_t)(q0 + lm) * 1024 + s * 16 + hi * 8;
    f4 a = *(const f4*)p, c = *(const f4*)(p + 4);
#pragma unroll
    for (int i = 0; i < 4; ++i) {
      qf[s][i] = (_Float16)(a[i] * LOG2E);
      qf[s][4 + i] = (_Float16)(c[i] * LOG2E);
    }
  }

  f16v O1[2] = {}, O5[2] = {};  // O^T[d][q], dtile 0/1
  float mr = -INFINITY, S1 = 0.f, S5 = 0.f;

  // ---- staging: K row-owner (krow=tid&63, 16 floats), V column-gather ----
  f4 kf[4];
  float vreg[2][8];
  const int krow = tid & 63, kq = tid >> 6;       // K: row krow, float cols kq*16..+16
  const int vd = tid & 63, vo0 = (tid >> 6) * 2;  // V: d-col vd, k-octets vo0, vo0+1

  auto LOADK = [&](int k0) {
#pragma unroll
    for (int j = 0; j < 4; ++j)
      kf[j] = *(const f4*)(Kb + (size_t)(k0 + krow) * 1024 + kq * 16 + 4 * j);
  };
  auto LOADV = [&](int k0) {  // coalesced: 64 lanes read consecutive d
#pragma unroll
    for (int i = 0; i < 2; ++i) {
      const float* p = Vb + (size_t)(k0 + (vo0 + i) * 8) * 1024 + vd;
#pragma unroll
      for (int j = 0; j < 8; ++j) vreg[i][j] = p[(size_t)j * 1024];
    }
  };
  auto STORE = [&](int buf) {
#pragma unroll
    for (int i = 0; i < 2; ++i) {  // K: two b128 stores, conflict-free slots
      u4v wv = {pku(kf[2 * i][0], kf[2 * i][1]), pku(kf[2 * i][2], kf[2 * i][3]),
                pku(kf[2 * i + 1][0], kf[2 * i + 1][1]), pku(kf[2 * i + 1][2], kf[2 * i + 1][3])};
      int col = (kq * 16 + 8 * i) ^ ((krow & 7) << 3);
      *(h8*)&Ks[buf][krow * 64 + col] = __builtin_bit_cast(h8, wv);
    }
#pragma unroll
    for (int i = 0; i < 2; ++i) {  // V^T: b128 stores
      u4v wv = {pku(vreg[i][0], vreg[i][1]), pku(vreg[i][2], vreg[i][3]),
                pku(vreg[i][4], vreg[i][5]), pku(vreg[i][6], vreg[i][7])};
      int col = ((vo0 + i) * 8) ^ ((vd & 7) << 3);
      *(h8*)&Vts[buf][vd * 64 + col] = __builtin_bit_cast(h8, wv);
    }
  };

  LOADK(0);
  LOADV(0);
  STORE(0);
  LOADK(KB);
  LOADV(KB);
  __syncthreads();

#pragma unroll 1
  for (int t = 0; t < NT; ++t) {
    const int cur = t & 1;
    if (t + 1 < NT) STORE(cur ^ 1);  // regs(t+1) -> idle buffer, overlaps compute
    if (t + 2 < NT) {
      LOADK((t + 2) * KB);
      LOADV((t + 2) * KB);
    }

    // ---- QK^T (swapped): sc[kh] = S[k = 32kh + row(reg,hi)][q = lm] ----
    f16v sc[2] = {};
    __builtin_amdgcn_s_setprio(1);
#pragma unroll
    for (int s = 0; s < 4; ++s) {
      h8 a0 = *(const h8*)&Ks[cur][lm * 64 + ((s * 16 + hi * 8) ^ swz)];
      h8 a1 = *(const h8*)&Ks[cur][(32 + lm) * 64 + ((s * 16 + hi * 8) ^ swz)];
      sc[0] = mm32(a0, qf[s], sc[0]);
      sc[1] = mm32(a1, qf[s], sc[1]);
    }
    __builtin_amdgcn_s_setprio(0);

    // ---- online softmax: lane + lane^32 together hold all 64 k of query lm ----
    float tm = -INFINITY;
#pragma unroll
    for (int kh = 0; kh < 2; ++kh)
#pragma unroll
      for (int r = 0; r < 16; ++r) tm = fmaxf(tm, sc[kh][r]);
    tm = fmaxf(tm, __shfl_xor(tm, 32));
    if (__any(tm > mr)) {
      float nm = fmaxf(mr, tm);
      float f = __builtin_amdgcn_exp2f(mr - nm);
      float f2 = f * f, f5 = f2 * f2 * f;
      mr = nm;
      S1 *= f;
      S5 *= f5;
#pragma unroll
      for (int dt = 0; dt < 2; ++dt) {
        O1[dt] *= f;
        O5[dt] *= f5;
      }
    }

    // ---- per k-step: exp, in-register P frags (pk+permlane32_swap), PV ----
    float t1 = 0.f, t5 = 0.f;
#pragma unroll
    for (int s = 0; s < 4; ++s) {
      const int kh = s >> 1, s8 = (s & 1) * 8;
      float e[8], e5[8];
#pragma unroll
      for (int j = 0; j < 8; ++j) {
        e[j] = __builtin_amdgcn_exp2f(sc[kh][s8 + j] - mr);
        float e2 = e[j] * e[j];
        e5[j] = e2 * e2 * e[j];
        t1 += e[j];
        t5 += e5[j];
      }
      // B-frag words: w0=[x_lo|y_lo], w2=[x_hi|y_hi] from swap(x,y)
      auto rA = __builtin_amdgcn_permlane32_swap(pku(e[0], e[1]), pku(e[4], e[5]), false, false);
      auto rB = __builtin_amdgcn_permlane32_swap(pku(e[2], e[3]), pku(e[6], e[7]), false, false);
      u4v bwE = {(unsigned)rA[0], (unsigned)rB[0], (unsigned)rA[1], (unsigned)rB[1]};
      h8 bE = __builtin_bit_cast(h8, bwE);
      auto rC = __builtin_amdgcn_permlane32_swap(pku(e5[0], e5[1]), pku(e5[4], e5[5]), false, false);
      auto rD = __builtin_amdgcn_permlane32_swap(pku(e5[2], e5[3]), pku(e5[6], e5[7]), false, false);
      u4v bw5 = {(unsigned)rC[0], (unsigned)rD[0], (unsigned)rC[1], (unsigned)rD[1]};
      h8 b5 = __builtin_bit_cast(h8, bw5);

      h8 v0 = *(const h8*)&Vts[cur][lm * 64 + ((s * 16 + hi * 8) ^ swz)];
      h8 v1 = *(const h8*)&Vts[cur][(32 + lm) * 64 + ((s * 16 + hi * 8) ^ swz)];
      __builtin_amdgcn_s_setprio(1);
      O1[0] = mm32(v0, bE, O1[0]);
      O1[1] = mm32(v1, bE, O1[1]);
      O5[0] = mm32(v0, b5, O5[0]);
      O5[1] = mm32(v1, b5, O5[1]);
      __builtin_amdgcn_s_setprio(0);
    }
    t1 += __shfl_xor(t1, 32);
    t5 += __shfl_xor(t5, 32);
    S1 += t1;
    S5 += t5;

    __syncthreads();  // all reads of buf[cur] done; buf[cur^1] stores done
  }

  // ---- epilogue: out = (O5 + Z^4 O1) / (S5 + Z^4 S1), Z = S1 ----
  const float z = S1, z2 = z * z, z4 = z2 * z2;
  const float inv = 1.0f / (S5 + z4 * S1);
#pragma unroll
  for (int dt = 0; dt < 2; ++dt)
#pragma unroll
    for (int i = 0; i < 4; ++i) {
      f4 o;
#pragma unroll
      for (int j = 0; j < 4; ++j)
        o[j] = (O5[dt][4 * i + j] + z4 * O1[dt][4 * i + j]) * inv;
      *(f4*)(O + base + (size_t)(q0 + lm) * 1024 + dt * 32 + 8 * i + 4 * hi) = o;
    }
}

extern "C" void kernel_launch(void* const* d_in, const int* in_sizes, int n_in,
                              void* d_out, int out_size, void* d_ws, size_t ws_size,
                              hipStream_t stream) {
  const float* q = (const float*)d_in[0];
  const float* k = (const float*)d_in[1];
  const float* v = (const float*)d_in[2];
  float* o = (float*)d_out;
  dsa_mfma<<<dim3(512), dim3(256), 0, stream>>>(q, k, v, o);
}

// Round 6
// 91.349 us; speedup vs baseline: 1.1289x; 1.0197x over previous
//
#include <hip/hip_runtime.h>
#include <math.h>

// DynamicSparseAttention via MFMA flash (f16 operands, fp32 accum):
// out = (O5 + Z^4 O1) / (S5 + Z^4 S1), e = 2^(s*log2e - m'), Z = S1.
// R6: sums via ones-MFMA (no serial f32 adds), e^5 in packed f16 after
//     permlane, pairwise max tree. Double-buffered K/V, 1 barrier/tile.

typedef _Float16 h8 __attribute__((ext_vector_type(8)));
typedef float f4 __attribute__((ext_vector_type(4)));
typedef float f16v __attribute__((ext_vector_type(16)));
typedef unsigned int u4v __attribute__((ext_vector_type(4)));

constexpr int Sc = 2048, Hc = 16;
constexpr int KB = 64, NT = Sc / KB;
constexpr float LOG2E = 1.4426950408889634f;

__device__ __forceinline__ f16v mm32(h8 a, h8 b, f16v c) {
  return __builtin_amdgcn_mfma_f32_32x32x16_f16(a, b, c, 0, 0, 0);
}
__device__ __forceinline__ unsigned pku(float a, float b) {
  return __builtin_bit_cast(unsigned, __builtin_amdgcn_cvt_pkrtz(a, b));
}

__global__ __launch_bounds__(256, 2) void dsa_mfma(
    const float* __restrict__ Q, const float* __restrict__ K,
    const float* __restrict__ V, float* __restrict__ O) {
  __shared__ __align__(16) _Float16 Ks[2][64 * 64];   // [k][e], elem col ^= 8*(k&7)
  __shared__ __align__(16) _Float16 Vts[2][64 * 64];  // [d][k], elem col ^= 8*(d&7)

  const int tid = threadIdx.x;
  const int w = tid >> 6, lane = tid & 63, lm = lane & 31, hi = lane >> 5;
  const int swz = (lm & 7) << 3;

  // XCD-bijective swizzle: 512 blocks = 8 XCD x 64; each XCD owns 4 heads.
  const int blk = blockIdx.x;
  const int ww = (blk & 7) * 64 + (blk >> 3);
  const int qtb = ww & 15, bh = ww >> 4;
  const int b = bh >> 4, h = bh & 15;

  const size_t base = ((size_t)b * Sc * Hc + h) * 64;  // row stride = 1024 floats
  const float* Qb = Q + base;
  const float* Kb = K + base;
  const float* Vb = V + base;
  const int q0 = qtb * 128 + w * 32;

  // ---- Q fragments (B-operand): lane holds Q[q0+lm][s*16 + hi*8 + j]*log2e ----
  h8 qf[4];
#pragma unroll
  for (int s = 0; s < 4; ++s) {
    const float* p = Qb + (size_t)(q0 + lm) * 1024 + s * 16 + hi * 8;
    f4 a = *(const f4*)p, c = *(const f4*)(p + 4);
#pragma unroll
    for (int i = 0; i < 4; ++i) {
      qf[s][i] = (_Float16)(a[i] * LOG2E);
      qf[s][4 + i] = (_Float16)(c[i] * LOG2E);
    }
  }
  h8 ones;
#pragma unroll
  for (int i = 0; i < 8; ++i) ones[i] = (_Float16)1.0f;

  f16v O1[2] = {}, O5[2] = {};  // O^T[d][q], dtile 0/1
  f16v S1a = {}, S5a = {};      // ones-MFMA sum accumulators (all rows equal)
  float mr = -INFINITY;

  // ---- staging: K row-owner (krow=tid&63, 16 floats), V column-gather ----
  f4 kf[4];
  float vreg[2][8];
  const int krow = tid & 63, kq = tid >> 6;       // K: row krow, float cols kq*16..+16
  const int vd = tid & 63, vo0 = (tid >> 6) * 2;  // V: d-col vd, k-octets vo0, vo0+1

  auto LOADK = [&](int k0) {
#pragma unroll
    for (int j = 0; j < 4; ++j)
      kf[j] = *(const f4*)(Kb + (size_t)(k0 + krow) * 1024 + kq * 16 + 4 * j);
  };
  auto LOADV = [&](int k0) {  // coalesced: 64 lanes read consecutive d
#pragma unroll
    for (int i = 0; i < 2; ++i) {
      const float* p = Vb + (size_t)(k0 + (vo0 + i) * 8) * 1024 + vd;
#pragma unroll
      for (int j = 0; j < 8; ++j) vreg[i][j] = p[(size_t)j * 1024];
    }
  };
  auto STORE = [&](int buf) {
#pragma unroll
    for (int i = 0; i < 2; ++i) {  // K: two b128 stores
      u4v wv = {pku(kf[2 * i][0], kf[2 * i][1]), pku(kf[2 * i][2], kf[2 * i][3]),
                pku(kf[2 * i + 1][0], kf[2 * i + 1][1]), pku(kf[2 * i + 1][2], kf[2 * i + 1][3])};
      int col = (kq * 16 + 8 * i) ^ ((krow & 7) << 3);
      *(h8*)&Ks[buf][krow * 64 + col] = __builtin_bit_cast(h8, wv);
    }
#pragma unroll
    for (int i = 0; i < 2; ++i) {  // V^T: b128 stores
      u4v wv = {pku(vreg[i][0], vreg[i][1]), pku(vreg[i][2], vreg[i][3]),
                pku(vreg[i][4], vreg[i][5]), pku(vreg[i][6], vreg[i][7])};
      int col = ((vo0 + i) * 8) ^ ((vd & 7) << 3);
      *(h8*)&Vts[buf][vd * 64 + col] = __builtin_bit_cast(h8, wv);
    }
  };

  LOADK(0);
  LOADV(0);
  STORE(0);
  LOADK(KB);
  LOADV(KB);
  __syncthreads();

#pragma unroll 1
  for (int t = 0; t < NT; ++t) {
    const int cur = t & 1;
    if (t + 1 < NT) STORE(cur ^ 1);  // regs(t+1) -> idle buffer, overlaps compute
    if (t + 2 < NT) {
      LOADK((t + 2) * KB);
      LOADV((t + 2) * KB);
    }

    // ---- QK^T (swapped): sc[kh] = S[k = 32kh + row(reg,hi)][q = lm] ----
    f16v sc[2] = {};
    __builtin_amdgcn_s_setprio(1);
#pragma unroll
    for (int s = 0; s < 4; ++s) {
      h8 a0 = *(const h8*)&Ks[cur][lm * 64 + ((s * 16 + hi * 8) ^ swz)];
      h8 a1 = *(const h8*)&Ks[cur][(32 + lm) * 64 + ((s * 16 + hi * 8) ^ swz)];
      sc[0] = mm32(a0, qf[s], sc[0]);
      sc[1] = mm32(a1, qf[s], sc[1]);
    }
    __builtin_amdgcn_s_setprio(0);

    // ---- tile max: pairwise tree (depth 5), then cross-half ----
    float m16[16];
#pragma unroll
    for (int r = 0; r < 16; ++r) m16[r] = fmaxf(sc[0][r], sc[1][r]);
#pragma unroll
    for (int d = 8; d >= 1; d >>= 1)
#pragma unroll
      for (int r = 0; r < d; ++r) m16[r] = fmaxf(m16[r], m16[r + d]);
    float tm = fmaxf(m16[0], __shfl_xor(m16[0], 32));
    if (__any(tm > mr)) {  // rescale only on a new running max
      float nm = fmaxf(mr, tm);
      float f = __builtin_amdgcn_exp2f(mr - nm);
      float f2 = f * f, f5 = f2 * f2 * f;
      mr = nm;
      S1a *= f;
      S5a *= f5;
#pragma unroll
      for (int dt = 0; dt < 2; ++dt) {
        O1[dt] *= f;
        O5[dt] *= f5;
      }
    }

    // ---- per k-step: exp, in-reg P frags, b5 = bE^5 (pk f16), PV + sums ----
#pragma unroll
    for (int s = 0; s < 4; ++s) {
      const int kh = s >> 1, s8 = (s & 1) * 8;
      float e[8];
#pragma unroll
      for (int j = 0; j < 8; ++j) e[j] = __builtin_amdgcn_exp2f(sc[kh][s8 + j] - mr);
      auto rA = __builtin_amdgcn_permlane32_swap(pku(e[0], e[1]), pku(e[4], e[5]), false, false);
      auto rB = __builtin_amdgcn_permlane32_swap(pku(e[2], e[3]), pku(e[6], e[7]), false, false);
      u4v bwE = {(unsigned)rA[0], (unsigned)rB[0], (unsigned)rA[1], (unsigned)rB[1]};
      h8 bE = __builtin_bit_cast(h8, bwE);
      h8 b2 = bE * bE, b4 = b2 * b2, b5 = b4 * bE;  // v_pk_mul_f16

      h8 v0 = *(const h8*)&Vts[cur][lm * 64 + ((s * 16 + hi * 8) ^ swz)];
      h8 v1 = *(const h8*)&Vts[cur][(32 + lm) * 64 + ((s * 16 + hi * 8) ^ swz)];
      __builtin_amdgcn_s_setprio(1);
      O1[0] = mm32(v0, bE, O1[0]);
      O1[1] = mm32(v1, bE, O1[1]);
      S1a = mm32(ones, bE, S1a);
      O5[0] = mm32(v0, b5, O5[0]);
      O5[1] = mm32(v1, b5, O5[1]);
      S5a = mm32(ones, b5, S5a);
      __builtin_amdgcn_s_setprio(0);
    }

    __syncthreads();  // all reads of buf[cur] done; buf[cur^1] stores done
  }

  // ---- epilogue: out = (O5 + Z^4 O1) / (S5 + Z^4 S1), Z = S1 ----
  const float z = S1a[0], z2 = z * z, z4 = z2 * z2;
  const float inv = 1.0f / (S5a[0] + z4 * S1a[0]);
#pragma unroll
  for (int dt = 0; dt < 2; ++dt)
#pragma unroll
    for (int i = 0; i < 4; ++i) {
      f4 o;
#pragma unroll
      for (int j = 0; j < 4; ++j)
        o[j] = (O5[dt][4 * i + j] + z4 * O1[dt][4 * i + j]) * inv;
      *(f4*)(O + base + (size_t)(q0 + lm) * 1024 + dt * 32 + 8 * i + 4 * hi) = o;
    }
}

extern "C" void kernel_launch(void* const* d_in, const int* in_sizes, int n_in,
                              void* d_out, int out_size, void* d_ws, size_t ws_size,
                              hipStream_t stream) {
  const float* q = (const float*)d_in[0];
  const float* k = (const float*)d_in[1];
  const float* v = (const float*)d_in[2];
  float* o = (float*)d_out;
  dsa_mfma<<<dim3(512), dim3(256), 0, stream>>>(q, k, v, o);
}